// Round 8
// baseline (115.467 us; speedup 1.0000x reference)
//
#include <hip/hip_runtime.h>
#include <stdint.h>

// Problem constants (fixed by the reference): x is (128,1,512,512) fp32, k=2048.
#define B        128
#define ROW_N    262144                 // 512*512 elements per row
#define THREADS  256
#define BLOCKS_PER_ROW 16
#define BLK_CHUNK (ROW_N / BLOCKS_PER_ROW)   // 16384 floats per block
#define WAVE_CHUNK 4096                      // floats per wave (4 waves/block)
#define WAVE_CAP 512                         // per-wave candidate cap (mean ~184, +25 sigma)
#define WPR      64                          // waves per row (16 blocks x 4 waves)

// Speculative exact pre-filter: keep ALL elements with |x| >= 2.0.
// k-th |x| ~= 2.66 for N(0,1); >=2.0 population ~11.9k +- 107 per row.
// n >= K guarantees the exact top-k lies in the candidate set. Any violation
// (per-wave cap, n < K, tie-bucket cap) -> inline exact fallback.
#define B0_BITS  0x40000000u  // bit pattern of 2.0f (abs-bits compare)
#define FKSHIFT  17           // 14-bit fine key for tie resolution
#define FB0      8192         // (B0_BITS >> FKSHIFT)
#define NFB      8192         // fine buckets [8192, 16384)
#define TIE_CAP  2048         // ties in one fine bucket (mean ~190)
#define THREADS_SS 512        // select_scatter block size (8 waves)
// inline fallback (normally never runs)
#define KSHIFT   19
#define NBUCKET  4096
#define FB_TIE_CAP 4096

// workspace layout (bytes) — nothing needs pre-zeroing (every slot we read is
// unconditionally written by scan_zero), so NO memset dispatch.
#define OFF_WCNT 0                          // B*WPR u32 per-wave true counts (32 KB)
#define OFF_CAND 32768                      // B*WPR*WAVE_CAP*uint2 = 32 MiB, segmented

typedef float vfloat4 __attribute__((ext_vector_type(4)));

// R7 = R6 resubmit (R6 failed with an infra UnresponsiveContainer error; code
// audited for barrier divergence / unbounded loops / ws overrun — none found).
// Theory (R6): R4's table showed the vendor fill kernel writes ws at 6.8 TB/s
// but OUR out buffer at only 1.6 TB/s — the ~1.67 TB/s ceiling is a PROPERTY
// OF THE d_out ALLOCATION, not of our access pattern. That retro-explains all
// six null scan experiments (R0-R5): scan_zero is pinned at ~90 us by 134 MB
// of out-writes; x reads (~18 us, R3) were never slow. Floor = ~84 us + tail.
// This round attacks the ~13 us tail: segmented atomic-free candidates (drops
// the ws-memset dispatch), fallback merged into select (drops a launch), and
// a parallel block scan replacing select's serial 512-iteration t==0 loop.

// ---- pass A: ONE barrier-free fused pass: zero-fill out + compact |x|>=2 ----
__global__ __launch_bounds__(THREADS) void scan_zero_kernel(const float* __restrict__ x,
                                                            float* __restrict__ out,
                                                            unsigned* __restrict__ wave_cnt,
                                                            uint2* __restrict__ cand) {
    __shared__ uint2 wbuf[THREADS / 64][WAVE_CAP];   // 16 KiB, wave-private slices
    const int t = threadIdx.x;
    const int w = t >> 6;
    const int lane = t & 63;
    const unsigned long long lt = (1ull << lane) - 1ull;
    const int row = blockIdx.y;
    const int wbase = blockIdx.x * BLK_CHUNK + w * WAVE_CHUNK;  // float offset in row
    const float4* src = (const float4*)(x + (size_t)row * ROW_N + wbase);
    vfloat4* dst = (vfloat4*)(out + (size_t)row * ROW_N + wbase);
    uint2* wb = wbuf[w];
    unsigned wcnt = 0;   // wave-uniform (derived from ballots only)
    const vfloat4 z = {0.f, 0.f, 0.f, 0.f};

    // all 16 coalesced loads in flight up front
    float4 v[16];
#pragma unroll
    for (int u = 0; u < 16; ++u) v[u] = src[u * 64 + lane];

#pragma unroll
    for (int u = 0; u < 16; ++u) {
        const unsigned fbase = (unsigned)(wbase + (u * 64 + lane) * 4);
        const unsigned bb[4] = {__float_as_uint(v[u].x), __float_as_uint(v[u].y),
                                __float_as_uint(v[u].z), __float_as_uint(v[u].w)};
#pragma unroll
        for (int c = 0; c < 4; ++c) {
            const bool pred = (bb[c] & 0x7FFFFFFFu) >= B0_BITS;   // ~4.5%
            const unsigned long long mask = __ballot(pred);
            if (pred) {
                const unsigned p = wcnt + (unsigned)__popcll(mask & lt);
                if (p < WAVE_CAP) wb[p] = make_uint2(fbase + (unsigned)c, bb[c]);
            }
            wcnt += (unsigned)__popcll(mask);
        }
        dst[u * 64 + lane] = z;   // zero-fill (out-buffer write ceiling ~1.67 TB/s)
    }

    // segmented flush: no atomics, no pre-zeroed counters
    const unsigned seg = (unsigned)((row << 6) + ((int)blockIdx.x << 2) + w);
    if (lane == 0) wave_cnt[seg] = wcnt;               // true count (cap detect)
    uint2* rcand = cand + (size_t)seg * WAVE_CAP;
    const unsigned total = wcnt < WAVE_CAP ? wcnt : WAVE_CAP;
    for (unsigned i = (unsigned)lane; i < total; i += 64) rcand[i] = wb[i];
}

// -- select+scatter+fallback fused: per row, hist over candidates, exact top-k
__global__ __launch_bounds__(THREADS_SS) void select_scatter_kernel(
        const float* __restrict__ x, const uint2* __restrict__ cand,
        const unsigned* __restrict__ wave_cnt, const int* __restrict__ topk,
        float* __restrict__ out) {
    const int row = blockIdx.x;
    const int t = threadIdx.x;
    const int w = t >> 6;        // 8 waves
    const int lane = t & 63;
    const unsigned K = (unsigned)(*topk);
    float* rout = out + (size_t)row * ROW_N;

    // LDS union: select uses h[NFB]+tidx[TIE_CAP]+tbits[TIE_CAP] (48 KB);
    // fallback reuses the same pool as fh[4096]+ftidx[4096]+ftbits[4096].
    __shared__ unsigned smem[NFB + 2 * TIE_CAP];   // 12288 words = 48 KiB
    __shared__ unsigned scnt_s[WPR];
    __shared__ unsigned wsum[8], wbase_s[8];
    __shared__ unsigned tcnt, sn;
    __shared__ int sb, sneed, sof;

    // per-wave counts -> n, overflow (wave 0)
    if (t < WPR) {
        const unsigned c = wave_cnt[(row << 6) + t];
        scnt_s[t] = c;
        unsigned tot = c;
#pragma unroll
        for (int d = 1; d < 64; d <<= 1) tot += __shfl_xor(tot, d);
        const int ofl = __any(c > (unsigned)WAVE_CAP) ? 1 : 0;
        if (t == 0) { sn = tot; sof = ofl; }
    }
    if (t == 0) tcnt = 0;
    __syncthreads();
    const unsigned n = sn;
    bool bad = (n < K) || (sof != 0);   // block-uniform

    unsigned* h = smem;
    unsigned* tidx = smem + NFB;
    unsigned* tbits = smem + NFB + TIE_CAP;

    if (!bad) {
        for (int i = t; i < NFB; i += THREADS_SS) h[i] = 0;
        __syncthreads();

        // histogram over segmented candidates
        for (int seg = 0; seg < WPR; ++seg) {
            const unsigned cn = scnt_s[seg];
            const uint2* sc = cand + ((size_t)(row << 6) + seg) * WAVE_CAP;
            for (unsigned i = (unsigned)t; i < cn; i += THREADS_SS)
                atomicAdd(&h[((sc[i].y & 0x7FFFFFFFu) >> FKSHIFT) - FB0], 1u);
        }
        __syncthreads();

        // suffix scan from the top bucket — parallel block scan (no serial loop)
        const int PER = NFB / THREADS_SS;   // 16
        unsigned s = 0;
#pragma unroll
        for (int i = 0; i < PER; ++i) s += h[NFB - 1 - (t * PER + i)];
        unsigned incl = s;
#pragma unroll
        for (int d = 1; d < 64; d <<= 1) {
            const unsigned nv = __shfl_up(incl, d);
            if (lane >= d) incl += nv;
        }
        if (lane == 63) wsum[w] = incl;
        __syncthreads();
        if (t < 8) {
            const unsigned v0 = wsum[t];
            unsigned inc2 = v0;
#pragma unroll
            for (int d = 1; d < 8; d <<= 1) {
                const unsigned nv = __shfl_up(inc2, d);
                if (t >= d) inc2 += nv;
            }
            wbase_s[t] = inc2 - v0;
        }
        __syncthreads();
        unsigned cum = wbase_s[w] + incl - s;
#pragma unroll
        for (int i = 0; i < PER; ++i) {
            const int brel = NFB - 1 - (t * PER + i);
            const unsigned c = h[brel];
            if (cum < K && cum + c >= K) {   // unique crossing
                sb = brel + FB0;
                sneed = (int)(K - cum);
            }
            cum += c;
        }
        __syncthreads();
        if (h[sb - FB0] > (unsigned)TIE_CAP) bad = true;   // block-uniform read
    }

    if (!bad) {
        const int b = sb;
        const int need = sneed;
        // scatter winners above the tie bucket; collect ties
        for (int seg = 0; seg < WPR; ++seg) {
            const unsigned cn = scnt_s[seg];
            const uint2* sc = cand + ((size_t)(row << 6) + seg) * WAVE_CAP;
            for (unsigned i = (unsigned)t; i < cn; i += THREADS_SS) {
                const uint2 e = sc[i];
                const int fk = (int)((e.y & 0x7FFFFFFFu) >> FKSHIFT);
                if (fk > b) {
                    rout[e.x] = __uint_as_float(e.y);
                } else if (fk == b) {
                    const unsigned p = atomicAdd(&tcnt, 1u);
                    tidx[p] = e.x; tbits[p] = e.y;   // p < TIE_CAP (hist check)
                }
            }
        }
        __syncthreads();
        // exact rank among ties: desc |x| bits, asc index (matches lax.top_k)
        const int c = (int)tcnt;
        for (int i = t; i < c; i += THREADS_SS) {
            const unsigned bits = tbits[i], idx = tidx[i];
            const uint64_t key = ((uint64_t)(bits & 0x7FFFFFFFu) << 32) | (uint64_t)(~idx);
            int rank = 0;
            for (int j = 0; j < c; ++j) {
                const uint64_t kj = ((uint64_t)(tbits[j] & 0x7FFFFFFFu) << 32) | (uint64_t)(~tidx[j]);
                rank += (kj > key) ? 1 : 0;
            }
            if (rank < need) rout[idx] = __uint_as_float(bits);
        }
        return;
    }

    // ---- inline exact fallback (normally never runs): full-row rescan -------
    __syncthreads();   // everyone done reading select's smem before reuse
    unsigned* fh = smem;                       // 4096
    unsigned* ftidx = smem + NBUCKET;          // 4096
    unsigned* ftbits = smem + 2 * NBUCKET;     // 4096
    const float4* xr = (const float4*)(x + (size_t)row * ROW_N);

    for (int i = t; i < NBUCKET; i += THREADS_SS) fh[i] = 0;
    if (t == 0) tcnt = 0;
    __syncthreads();

    for (int i4 = t; i4 < ROW_N / 4; i4 += THREADS_SS) {
        const float4 v = xr[i4];
        atomicAdd(&fh[(__float_as_uint(v.x) & 0x7FFFFFFFu) >> KSHIFT], 1u);
        atomicAdd(&fh[(__float_as_uint(v.y) & 0x7FFFFFFFu) >> KSHIFT], 1u);
        atomicAdd(&fh[(__float_as_uint(v.z) & 0x7FFFFFFFu) >> KSHIFT], 1u);
        atomicAdd(&fh[(__float_as_uint(v.w) & 0x7FFFFFFFu) >> KSHIFT], 1u);
    }
    __syncthreads();

    const int PER = NBUCKET / THREADS_SS;   // 8
    unsigned s = 0;
#pragma unroll
    for (int i = 0; i < PER; ++i) s += fh[NBUCKET - 1 - (t * PER + i)];
    unsigned incl = s;
#pragma unroll
    for (int d = 1; d < 64; d <<= 1) {
        const unsigned nv = __shfl_up(incl, d);
        if (lane >= d) incl += nv;
    }
    if (lane == 63) wsum[w] = incl;
    __syncthreads();
    if (t < 8) {
        const unsigned v0 = wsum[t];
        unsigned inc2 = v0;
#pragma unroll
        for (int d = 1; d < 8; d <<= 1) {
            const unsigned nv = __shfl_up(inc2, d);
            if (t >= d) inc2 += nv;
        }
        wbase_s[t] = inc2 - v0;
    }
    __syncthreads();
    unsigned cum = wbase_s[w] + incl - s;
#pragma unroll
    for (int i = 0; i < PER; ++i) {
        const int bucket = NBUCKET - 1 - (t * PER + i);
        const unsigned c = fh[bucket];
        if (cum < K && cum + c >= K) { sb = bucket; sneed = (int)(K - cum); }
        cum += c;
    }
    __syncthreads();
    const int b = sb;
    const int need = sneed;

    for (int i4 = t; i4 < ROW_N / 4; i4 += THREADS_SS) {
        const float4 v = xr[i4];
        const unsigned bits4[4] = {__float_as_uint(v.x), __float_as_uint(v.y),
                                   __float_as_uint(v.z), __float_as_uint(v.w)};
#pragma unroll
        for (int c = 0; c < 4; ++c) {
            const int key = (int)((bits4[c] & 0x7FFFFFFFu) >> KSHIFT);
            if (key > b) {
                rout[i4 * 4 + c] = __uint_as_float(bits4[c]);
            } else if (key == b) {
                const unsigned p = atomicAdd(&tcnt, 1u);
                if (p < FB_TIE_CAP) { ftidx[p] = (unsigned)(i4 * 4 + c); ftbits[p] = bits4[c]; }
            }
        }
    }
    __syncthreads();
    const int c = (int)(tcnt < (unsigned)FB_TIE_CAP ? tcnt : (unsigned)FB_TIE_CAP);
    for (int i = t; i < c; i += THREADS_SS) {
        const unsigned bits = ftbits[i], idx = ftidx[i];
        const uint64_t key = ((uint64_t)(bits & 0x7FFFFFFFu) << 32) | (uint64_t)(~idx);
        int rank = 0;
        for (int j = 0; j < c; ++j) {
            const uint64_t kj = ((uint64_t)(ftbits[j] & 0x7FFFFFFFu) << 32) | (uint64_t)(~ftidx[j]);
            rank += (kj > key) ? 1 : 0;
        }
        if (rank < need) rout[idx] = __uint_as_float(bits);
    }
}

extern "C" void kernel_launch(void* const* d_in, const int* in_sizes, int n_in,
                              void* d_out, int out_size, void* d_ws, size_t ws_size,
                              hipStream_t stream) {
    const float* x = (const float*)d_in[0];
    const int* topk = (const int*)d_in[1];
    float* out = (float*)d_out;
    char* ws = (char*)d_ws;

    unsigned* wave_cnt = (unsigned*)(ws + OFF_WCNT);
    uint2* cand        = (uint2*)(ws + OFF_CAND);

    // no memset: every workspace slot we read is unconditionally written

    dim3 gridA(BLOCKS_PER_ROW, B);  // 16 x 128 = 2048 blocks
    scan_zero_kernel<<<gridA, THREADS, 0, stream>>>(x, out, wave_cnt, cand);
    select_scatter_kernel<<<B, THREADS_SS, 0, stream>>>(x, cand, wave_cnt, topk, out);
}

// Round 9
// 110.823 us; speedup vs baseline: 1.0419x; 1.0419x over previous
//
#include <hip/hip_runtime.h>
#include <stdint.h>

// Problem constants (fixed by the reference): x is (128,1,512,512) fp32, k=2048.
#define B        128
#define ROW_N    262144                 // 512*512 elements per row
#define THREADS  256
#define BLOCKS_PER_ROW 16
#define BLK_CHUNK (ROW_N / BLOCKS_PER_ROW)   // 16384 floats per block
#define WAVE_CHUNK 4096                      // floats per wave (4 waves/block)
#define WAVE_CAP 512                         // per-wave candidate cap (mean ~184, +25 sigma)
#define WPR      64                          // waves per row (16 blocks x 4 waves)
#define ROW_SLOTS (WPR * WAVE_CAP)           // 32768 candidate slots per row

// Speculative exact pre-filter: keep ALL elements with |x| >= 2.0.
// k-th |x| ~= 2.66 for N(0,1); >=2.0 population ~11.9k +- 107 per row.
// n >= K guarantees the exact top-k lies in the candidate set. Any violation
// (per-wave cap, n < K, tie-bucket cap) -> inline exact fallback.
#define B0_BITS  0x40000000u  // bit pattern of 2.0f (abs-bits compare)
#define FKSHIFT  17           // 14-bit fine key for tie resolution
#define FB0      8192         // (B0_BITS >> FKSHIFT)
#define NFB      8192         // fine buckets [8192, 16384)
#define TIE_CAP  2048         // ties in one fine bucket (mean ~190)
#define THREADS_SS 512        // select_scatter block size (8 waves)
// inline fallback (normally never runs)
#define KSHIFT   19
#define NBUCKET  4096
#define FB_TIE_CAP 4096

// workspace layout (bytes) — nothing needs pre-zeroing (every slot we read is
// unconditionally written by scan_zero), so NO memset dispatch.
#define OFF_WCNT 0                          // B*WPR u32 per-wave true counts (32 KB)
#define OFF_CAND 32768                      // B*ROW_SLOTS*uint2 = 32 MiB, segmented

typedef float vfloat4 __attribute__((ext_vector_type(4)));

// R9: R8 evidence — scan_zero 81.6 us == vendor blit on out (80.8 us): the
// scan is AT the d_out write floor (~1.67 TB/s allocation property). But R6's
// segmented select regressed ~6 -> ~30 us: the per-segment loop (64 segs x
// ~184 entries) is 64 serial memory-latency round-trips x 2 passes. Fix:
// FLATTEN — candidate slots for a row are contiguous (seg*512+i), so iterate
// g = t..32767 step 512 with predicated load (i < cnt[seg]). No cross-
// iteration dependency -> loads pipeline at bandwidth, not latency.

// ---- pass A: ONE barrier-free fused pass: zero-fill out + compact |x|>=2 ----
__global__ __launch_bounds__(THREADS) void scan_zero_kernel(const float* __restrict__ x,
                                                            float* __restrict__ out,
                                                            unsigned* __restrict__ wave_cnt,
                                                            uint2* __restrict__ cand) {
    __shared__ uint2 wbuf[THREADS / 64][WAVE_CAP];   // 16 KiB, wave-private slices
    const int t = threadIdx.x;
    const int w = t >> 6;
    const int lane = t & 63;
    const unsigned long long lt = (1ull << lane) - 1ull;
    const int row = blockIdx.y;
    const int wbase = blockIdx.x * BLK_CHUNK + w * WAVE_CHUNK;  // float offset in row
    const float4* src = (const float4*)(x + (size_t)row * ROW_N + wbase);
    vfloat4* dst = (vfloat4*)(out + (size_t)row * ROW_N + wbase);
    uint2* wb = wbuf[w];
    unsigned wcnt = 0;   // wave-uniform (derived from ballots only)
    const vfloat4 z = {0.f, 0.f, 0.f, 0.f};

    // all 16 coalesced loads in flight up front
    float4 v[16];
#pragma unroll
    for (int u = 0; u < 16; ++u) v[u] = src[u * 64 + lane];

#pragma unroll
    for (int u = 0; u < 16; ++u) {
        const unsigned fbase = (unsigned)(wbase + (u * 64 + lane) * 4);
        const unsigned bb[4] = {__float_as_uint(v[u].x), __float_as_uint(v[u].y),
                                __float_as_uint(v[u].z), __float_as_uint(v[u].w)};
#pragma unroll
        for (int c = 0; c < 4; ++c) {
            const bool pred = (bb[c] & 0x7FFFFFFFu) >= B0_BITS;   // ~4.5%
            const unsigned long long mask = __ballot(pred);
            if (pred) {
                const unsigned p = wcnt + (unsigned)__popcll(mask & lt);
                if (p < WAVE_CAP) wb[p] = make_uint2(fbase + (unsigned)c, bb[c]);
            }
            wcnt += (unsigned)__popcll(mask);
        }
        dst[u * 64 + lane] = z;   // zero-fill (out-buffer write ceiling ~1.67 TB/s)
    }

    // segmented flush: no atomics, no pre-zeroed counters
    const unsigned seg = (unsigned)((row << 6) + ((int)blockIdx.x << 2) + w);
    if (lane == 0) wave_cnt[seg] = wcnt;               // true count (cap detect)
    uint2* rcand = cand + (size_t)seg * WAVE_CAP;
    const unsigned total = wcnt < WAVE_CAP ? wcnt : WAVE_CAP;
    for (unsigned i = (unsigned)lane; i < total; i += 64) rcand[i] = wb[i];
}

// -- select+scatter+fallback fused: per row, hist over candidates, exact top-k
__global__ __launch_bounds__(THREADS_SS) void select_scatter_kernel(
        const float* __restrict__ x, const uint2* __restrict__ cand,
        const unsigned* __restrict__ wave_cnt, const int* __restrict__ topk,
        float* __restrict__ out) {
    const int row = blockIdx.x;
    const int t = threadIdx.x;
    const int w = t >> 6;        // 8 waves
    const int lane = t & 63;
    const unsigned K = (unsigned)(*topk);
    float* rout = out + (size_t)row * ROW_N;
    const uint2* rcand = cand + (size_t)row * ROW_SLOTS;   // contiguous row slots

    // LDS union: select uses h[NFB]+tidx[TIE_CAP]+tbits[TIE_CAP] (48 KB);
    // fallback reuses the same pool as fh[4096]+ftidx[4096]+ftbits[4096].
    __shared__ unsigned smem[NFB + 2 * TIE_CAP];   // 12288 words = 48 KiB
    __shared__ unsigned scnt_s[WPR];
    __shared__ unsigned wsum[8], wbase_s[8];
    __shared__ unsigned tcnt, sn;
    __shared__ int sb, sneed, sof;

    // per-wave counts -> n, overflow (wave 0)
    if (t < WPR) {
        const unsigned c = wave_cnt[(row << 6) + t];
        scnt_s[t] = c;
        unsigned tot = c;
#pragma unroll
        for (int d = 1; d < 64; d <<= 1) tot += __shfl_xor(tot, d);
        const int ofl = __any(c > (unsigned)WAVE_CAP) ? 1 : 0;
        if (t == 0) { sn = tot; sof = ofl; }
    }
    if (t == 0) tcnt = 0;
    __syncthreads();
    const unsigned n = sn;
    bool bad = (n < K) || (sof != 0);   // block-uniform

    unsigned* h = smem;
    unsigned* tidx = smem + NFB;
    unsigned* tbits = smem + NFB + TIE_CAP;

    if (!bad) {
        for (int i = t; i < NFB; i += THREADS_SS) h[i] = 0;
        __syncthreads();

        // histogram — flattened slot loop: 64 independent predicated loads
        for (unsigned g = (unsigned)t; g < (unsigned)ROW_SLOTS; g += THREADS_SS) {
            if ((g & (WAVE_CAP - 1)) < scnt_s[g >> 9])
                atomicAdd(&h[((rcand[g].y & 0x7FFFFFFFu) >> FKSHIFT) - FB0], 1u);
        }
        __syncthreads();

        // suffix scan from the top bucket — parallel block scan (no serial loop)
        const int PER = NFB / THREADS_SS;   // 16
        unsigned s = 0;
#pragma unroll
        for (int i = 0; i < PER; ++i) s += h[NFB - 1 - (t * PER + i)];
        unsigned incl = s;
#pragma unroll
        for (int d = 1; d < 64; d <<= 1) {
            const unsigned nv = __shfl_up(incl, d);
            if (lane >= d) incl += nv;
        }
        if (lane == 63) wsum[w] = incl;
        __syncthreads();
        if (t < 8) {
            const unsigned v0 = wsum[t];
            unsigned inc2 = v0;
#pragma unroll
            for (int d = 1; d < 8; d <<= 1) {
                const unsigned nv = __shfl_up(inc2, d);
                if (t >= d) inc2 += nv;
            }
            wbase_s[t] = inc2 - v0;
        }
        __syncthreads();
        unsigned cum = wbase_s[w] + incl - s;
#pragma unroll
        for (int i = 0; i < PER; ++i) {
            const int brel = NFB - 1 - (t * PER + i);
            const unsigned c = h[brel];
            if (cum < K && cum + c >= K) {   // unique crossing
                sb = brel + FB0;
                sneed = (int)(K - cum);
            }
            cum += c;
        }
        __syncthreads();
        if (h[sb - FB0] > (unsigned)TIE_CAP) bad = true;   // block-uniform read
    }

    if (!bad) {
        const int b = sb;
        const int need = sneed;
        // scatter winners above the tie bucket; collect ties — flattened
        for (unsigned g = (unsigned)t; g < (unsigned)ROW_SLOTS; g += THREADS_SS) {
            if ((g & (WAVE_CAP - 1)) < scnt_s[g >> 9]) {
                const uint2 e = rcand[g];
                const int fk = (int)((e.y & 0x7FFFFFFFu) >> FKSHIFT);
                if (fk > b) {
                    rout[e.x] = __uint_as_float(e.y);
                } else if (fk == b) {
                    const unsigned p = atomicAdd(&tcnt, 1u);
                    tidx[p] = e.x; tbits[p] = e.y;   // p < TIE_CAP (hist check)
                }
            }
        }
        __syncthreads();
        // exact rank among ties: desc |x| bits, asc index (matches lax.top_k)
        const int c = (int)tcnt;
        for (int i = t; i < c; i += THREADS_SS) {
            const unsigned bits = tbits[i], idx = tidx[i];
            const uint64_t key = ((uint64_t)(bits & 0x7FFFFFFFu) << 32) | (uint64_t)(~idx);
            int rank = 0;
            for (int j = 0; j < c; ++j) {
                const uint64_t kj = ((uint64_t)(tbits[j] & 0x7FFFFFFFu) << 32) | (uint64_t)(~tidx[j]);
                rank += (kj > key) ? 1 : 0;
            }
            if (rank < need) rout[idx] = __uint_as_float(bits);
        }
        return;
    }

    // ---- inline exact fallback (normally never runs): full-row rescan -------
    __syncthreads();   // everyone done reading select's smem before reuse
    unsigned* fh = smem;                       // 4096
    unsigned* ftidx = smem + NBUCKET;          // 4096
    unsigned* ftbits = smem + 2 * NBUCKET;     // 4096
    const float4* xr = (const float4*)(x + (size_t)row * ROW_N);

    for (int i = t; i < NBUCKET; i += THREADS_SS) fh[i] = 0;
    if (t == 0) tcnt = 0;
    __syncthreads();

    for (int i4 = t; i4 < ROW_N / 4; i4 += THREADS_SS) {
        const float4 v = xr[i4];
        atomicAdd(&fh[(__float_as_uint(v.x) & 0x7FFFFFFFu) >> KSHIFT], 1u);
        atomicAdd(&fh[(__float_as_uint(v.y) & 0x7FFFFFFFu) >> KSHIFT], 1u);
        atomicAdd(&fh[(__float_as_uint(v.z) & 0x7FFFFFFFu) >> KSHIFT], 1u);
        atomicAdd(&fh[(__float_as_uint(v.w) & 0x7FFFFFFFu) >> KSHIFT], 1u);
    }
    __syncthreads();

    const int PER = NBUCKET / THREADS_SS;   // 8
    unsigned s = 0;
#pragma unroll
    for (int i = 0; i < PER; ++i) s += fh[NBUCKET - 1 - (t * PER + i)];
    unsigned incl = s;
#pragma unroll
    for (int d = 1; d < 64; d <<= 1) {
        const unsigned nv = __shfl_up(incl, d);
        if (lane >= d) incl += nv;
    }
    if (lane == 63) wsum[w] = incl;
    __syncthreads();
    if (t < 8) {
        const unsigned v0 = wsum[t];
        unsigned inc2 = v0;
#pragma unroll
        for (int d = 1; d < 8; d <<= 1) {
            const unsigned nv = __shfl_up(inc2, d);
            if (t >= d) inc2 += nv;
        }
        wbase_s[t] = inc2 - v0;
    }
    __syncthreads();
    unsigned cum = wbase_s[w] + incl - s;
#pragma unroll
    for (int i = 0; i < PER; ++i) {
        const int bucket = NBUCKET - 1 - (t * PER + i);
        const unsigned c = fh[bucket];
        if (cum < K && cum + c >= K) { sb = bucket; sneed = (int)(K - cum); }
        cum += c;
    }
    __syncthreads();
    const int b = sb;
    const int need = sneed;

    for (int i4 = t; i4 < ROW_N / 4; i4 += THREADS_SS) {
        const float4 v = xr[i4];
        const unsigned bits4[4] = {__float_as_uint(v.x), __float_as_uint(v.y),
                                   __float_as_uint(v.z), __float_as_uint(v.w)};
#pragma unroll
        for (int c = 0; c < 4; ++c) {
            const int key = (int)((bits4[c] & 0x7FFFFFFFu) >> KSHIFT);
            if (key > b) {
                rout[i4 * 4 + c] = __uint_as_float(bits4[c]);
            } else if (key == b) {
                const unsigned p = atomicAdd(&tcnt, 1u);
                if (p < FB_TIE_CAP) { ftidx[p] = (unsigned)(i4 * 4 + c); ftbits[p] = bits4[c]; }
            }
        }
    }
    __syncthreads();
    const int c = (int)(tcnt < (unsigned)FB_TIE_CAP ? tcnt : (unsigned)FB_TIE_CAP);
    for (int i = t; i < c; i += THREADS_SS) {
        const unsigned bits = ftbits[i], idx = ftidx[i];
        const uint64_t key = ((uint64_t)(bits & 0x7FFFFFFFu) << 32) | (uint64_t)(~idx);
        int rank = 0;
        for (int j = 0; j < c; ++j) {
            const uint64_t kj = ((uint64_t)(ftbits[j] & 0x7FFFFFFFu) << 32) | (uint64_t)(~ftidx[j]);
            rank += (kj > key) ? 1 : 0;
        }
        if (rank < need) rout[idx] = __uint_as_float(bits);
    }
}

extern "C" void kernel_launch(void* const* d_in, const int* in_sizes, int n_in,
                              void* d_out, int out_size, void* d_ws, size_t ws_size,
                              hipStream_t stream) {
    const float* x = (const float*)d_in[0];
    const int* topk = (const int*)d_in[1];
    float* out = (float*)d_out;
    char* ws = (char*)d_ws;

    unsigned* wave_cnt = (unsigned*)(ws + OFF_WCNT);
    uint2* cand        = (uint2*)(ws + OFF_CAND);

    // no memset: every workspace slot we read is unconditionally written

    dim3 gridA(BLOCKS_PER_ROW, B);  // 16 x 128 = 2048 blocks
    scan_zero_kernel<<<gridA, THREADS, 0, stream>>>(x, out, wave_cnt, cand);
    select_scatter_kernel<<<B, THREADS_SS, 0, stream>>>(x, cand, wave_cnt, topk, out);
}

// Round 10
// 84.159 us; speedup vs baseline: 1.3720x; 1.3168x over previous
//
#include <hip/hip_runtime.h>
#include <stdint.h>

// Problem constants (fixed by the reference): x is (128,1,512,512) fp32, k=2048.
#define B        128
#define ROW_N    262144                 // 512*512 elements per row
#define THREADS  256
#define BLOCKS_PER_ROW 16
#define BLK_CHUNK (ROW_N / BLOCKS_PER_ROW)   // 16384 floats per block
#define WAVE_CHUNK 4096                      // floats per wave (4 waves/block)
#define WAVE_CAP 512                         // per-wave candidate cap (mean ~184, +25 sigma)
#define WPR      64                          // waves per row (16 blocks x 4 waves)
#define ROW_SLOTS (WPR * WAVE_CAP)           // 32768 candidate slots per row

// Speculative exact pre-filter: keep ALL elements with |x| >= 2.0.
// k-th |x| ~= 2.66 for N(0,1); >=2.0 population ~11.9k +- 107 per row.
// n >= K guarantees the exact top-k lies in the candidate set. Any violation
// (per-wave cap, n < K, tie-bucket cap) -> inline exact fallback.
#define B0_BITS  0x40000000u  // bit pattern of 2.0f (abs-bits compare)
#define FKSHIFT  17           // 14-bit fine key for tie resolution
#define FB0      8192         // (B0_BITS >> FKSHIFT)
#define NFB      8192         // fine buckets [8192, 16384)
#define TIE_CAP  2048         // ties in one fine bucket (mean ~190)
#define THREADS_SS 512        // select_scatter block size (8 waves)
// inline fallback (normally never runs)
#define KSHIFT   19
#define NBUCKET  4096
#define FB_TIE_CAP 4096

// workspace layout (bytes) — nothing needs pre-zeroing (every slot we read is
// unconditionally written by scan_zero), so NO memset dispatch.
#define OFF_WCNT 0                          // B*WPR u32 per-wave true counts (32 KB)
#define OFF_CAND 32768                      // B*ROW_SLOTS*uint2 = 32 MiB, segmented

typedef float vfloat4 __attribute__((ext_vector_type(4)));

// R10: R9's flatten was NULL because of the slot->wave mapping: iteration k
// touches only segment k, and within it wave w covers offsets [64w,64w+63].
// With cnt ~186 < 192, waves 0-2 do ALL the work and waves 3-7 are predicated
// off in every iteration — 5/8 of the block idle, 64 latency-chained
// iterations x 2 passes ~= the ~16 us regression vs R0's dense select. Fix:
// each wave OWNS 8 segments, preloads their counts to registers, iterates
// each densely i=lane..cnt step 64 (~3 fully-active iterations/segment).
// scan_zero untouched: 81.6 us == vendor blit on d_out (write-rate property
// of the allocation) — it is at its floor.

// ---- pass A: ONE barrier-free fused pass: zero-fill out + compact |x|>=2 ----
__global__ __launch_bounds__(THREADS) void scan_zero_kernel(const float* __restrict__ x,
                                                            float* __restrict__ out,
                                                            unsigned* __restrict__ wave_cnt,
                                                            uint2* __restrict__ cand) {
    __shared__ uint2 wbuf[THREADS / 64][WAVE_CAP];   // 16 KiB, wave-private slices
    const int t = threadIdx.x;
    const int w = t >> 6;
    const int lane = t & 63;
    const unsigned long long lt = (1ull << lane) - 1ull;
    const int row = blockIdx.y;
    const int wbase = blockIdx.x * BLK_CHUNK + w * WAVE_CHUNK;  // float offset in row
    const float4* src = (const float4*)(x + (size_t)row * ROW_N + wbase);
    vfloat4* dst = (vfloat4*)(out + (size_t)row * ROW_N + wbase);
    uint2* wb = wbuf[w];
    unsigned wcnt = 0;   // wave-uniform (derived from ballots only)
    const vfloat4 z = {0.f, 0.f, 0.f, 0.f};

    // all 16 coalesced loads in flight up front
    float4 v[16];
#pragma unroll
    for (int u = 0; u < 16; ++u) v[u] = src[u * 64 + lane];

#pragma unroll
    for (int u = 0; u < 16; ++u) {
        const unsigned fbase = (unsigned)(wbase + (u * 64 + lane) * 4);
        const unsigned bb[4] = {__float_as_uint(v[u].x), __float_as_uint(v[u].y),
                                __float_as_uint(v[u].z), __float_as_uint(v[u].w)};
#pragma unroll
        for (int c = 0; c < 4; ++c) {
            const bool pred = (bb[c] & 0x7FFFFFFFu) >= B0_BITS;   // ~4.5%
            const unsigned long long mask = __ballot(pred);
            if (pred) {
                const unsigned p = wcnt + (unsigned)__popcll(mask & lt);
                if (p < WAVE_CAP) wb[p] = make_uint2(fbase + (unsigned)c, bb[c]);
            }
            wcnt += (unsigned)__popcll(mask);
        }
        dst[u * 64 + lane] = z;   // zero-fill (out-buffer write ceiling ~1.67 TB/s)
    }

    // segmented flush: no atomics, no pre-zeroed counters
    const unsigned seg = (unsigned)((row << 6) + ((int)blockIdx.x << 2) + w);
    if (lane == 0) wave_cnt[seg] = wcnt;               // true count (cap detect)
    uint2* rcand = cand + (size_t)seg * WAVE_CAP;
    const unsigned total = wcnt < WAVE_CAP ? wcnt : WAVE_CAP;
    for (unsigned i = (unsigned)lane; i < total; i += 64) rcand[i] = wb[i];
}

// -- select+scatter+fallback fused: per row, hist over candidates, exact top-k
__global__ __launch_bounds__(THREADS_SS) void select_scatter_kernel(
        const float* __restrict__ x, const uint2* __restrict__ cand,
        const unsigned* __restrict__ wave_cnt, const int* __restrict__ topk,
        float* __restrict__ out) {
    const int row = blockIdx.x;
    const int t = threadIdx.x;
    const int w = t >> 6;        // 8 waves
    const int lane = t & 63;
    const unsigned K = (unsigned)(*topk);
    float* rout = out + (size_t)row * ROW_N;
    const uint2* rcand = cand + (size_t)row * ROW_SLOTS;   // contiguous row slots

    // LDS union: select uses h[NFB]+tidx[TIE_CAP]+tbits[TIE_CAP] (48 KB);
    // fallback reuses the same pool as fh[4096]+ftidx[4096]+ftbits[4096].
    __shared__ unsigned smem[NFB + 2 * TIE_CAP];   // 12288 words = 48 KiB
    __shared__ unsigned scnt_s[WPR];
    __shared__ unsigned wsum[8], wbase_s[8];
    __shared__ unsigned tcnt, sn;
    __shared__ int sb, sneed, sof;

    // per-wave counts -> n, overflow (wave 0)
    if (t < WPR) {
        const unsigned c = wave_cnt[(row << 6) + t];
        scnt_s[t] = c;
        unsigned tot = c;
#pragma unroll
        for (int d = 1; d < 64; d <<= 1) tot += __shfl_xor(tot, d);
        const int ofl = __any(c > (unsigned)WAVE_CAP) ? 1 : 0;
        if (t == 0) { sn = tot; sof = ofl; }
    }
    if (t == 0) tcnt = 0;
    __syncthreads();
    const unsigned n = sn;
    bool bad = (n < K) || (sof != 0);   // block-uniform

    unsigned* h = smem;
    unsigned* tidx = smem + NFB;
    unsigned* tbits = smem + NFB + TIE_CAP;

    // each wave owns segments [8w, 8w+8); preload counts to registers
    unsigned cn[8];
#pragma unroll
    for (int sI = 0; sI < 8; ++sI) {
        unsigned c = scnt_s[8 * w + sI];
        cn[sI] = c < (unsigned)WAVE_CAP ? c : (unsigned)WAVE_CAP;
    }

    if (!bad) {
        for (int i = t; i < NFB; i += THREADS_SS) h[i] = 0;
        __syncthreads();

        // histogram — per-wave dense segment loops (all 8 waves active)
#pragma unroll
        for (int sI = 0; sI < 8; ++sI) {
            const unsigned sb0 = (unsigned)(8 * w + sI) << 9;   // seg*512
            const unsigned c = cn[sI];
            for (unsigned i = (unsigned)lane; i < c; i += 64)
                atomicAdd(&h[((rcand[sb0 + i].y & 0x7FFFFFFFu) >> FKSHIFT) - FB0], 1u);
        }
        __syncthreads();

        // suffix scan from the top bucket — parallel block scan (no serial loop)
        const int PER = NFB / THREADS_SS;   // 16
        unsigned s = 0;
#pragma unroll
        for (int i = 0; i < PER; ++i) s += h[NFB - 1 - (t * PER + i)];
        unsigned incl = s;
#pragma unroll
        for (int d = 1; d < 64; d <<= 1) {
            const unsigned nv = __shfl_up(incl, d);
            if (lane >= d) incl += nv;
        }
        if (lane == 63) wsum[w] = incl;
        __syncthreads();
        if (t < 8) {
            const unsigned v0 = wsum[t];
            unsigned inc2 = v0;
#pragma unroll
            for (int d = 1; d < 8; d <<= 1) {
                const unsigned nv = __shfl_up(inc2, d);
                if (t >= d) inc2 += nv;
            }
            wbase_s[t] = inc2 - v0;
        }
        __syncthreads();
        unsigned cum = wbase_s[w] + incl - s;
#pragma unroll
        for (int i = 0; i < PER; ++i) {
            const int brel = NFB - 1 - (t * PER + i);
            const unsigned c = h[brel];
            if (cum < K && cum + c >= K) {   // unique crossing
                sb = brel + FB0;
                sneed = (int)(K - cum);
            }
            cum += c;
        }
        __syncthreads();
        if (h[sb - FB0] > (unsigned)TIE_CAP) bad = true;   // block-uniform read
    }

    if (!bad) {
        const int b = sb;
        const int need = sneed;
        // scatter winners above the tie bucket; collect ties — same dense loops
#pragma unroll
        for (int sI = 0; sI < 8; ++sI) {
            const unsigned sb0 = (unsigned)(8 * w + sI) << 9;
            const unsigned c = cn[sI];
            for (unsigned i = (unsigned)lane; i < c; i += 64) {
                const uint2 e = rcand[sb0 + i];
                const int fk = (int)((e.y & 0x7FFFFFFFu) >> FKSHIFT);
                if (fk > b) {
                    rout[e.x] = __uint_as_float(e.y);
                } else if (fk == b) {
                    const unsigned p = atomicAdd(&tcnt, 1u);
                    tidx[p] = e.x; tbits[p] = e.y;   // p < TIE_CAP (hist check)
                }
            }
        }
        __syncthreads();
        // exact rank among ties: desc |x| bits, asc index (matches lax.top_k)
        const int c = (int)tcnt;
        for (int i = t; i < c; i += THREADS_SS) {
            const unsigned bits = tbits[i], idx = tidx[i];
            const uint64_t key = ((uint64_t)(bits & 0x7FFFFFFFu) << 32) | (uint64_t)(~idx);
            int rank = 0;
            for (int j = 0; j < c; ++j) {
                const uint64_t kj = ((uint64_t)(tbits[j] & 0x7FFFFFFFu) << 32) | (uint64_t)(~tidx[j]);
                rank += (kj > key) ? 1 : 0;
            }
            if (rank < need) rout[idx] = __uint_as_float(bits);
        }
        return;
    }

    // ---- inline exact fallback (normally never runs): full-row rescan -------
    __syncthreads();   // everyone done reading select's smem before reuse
    unsigned* fh = smem;                       // 4096
    unsigned* ftidx = smem + NBUCKET;          // 4096
    unsigned* ftbits = smem + 2 * NBUCKET;     // 4096
    const float4* xr = (const float4*)(x + (size_t)row * ROW_N);

    for (int i = t; i < NBUCKET; i += THREADS_SS) fh[i] = 0;
    if (t == 0) tcnt = 0;
    __syncthreads();

    for (int i4 = t; i4 < ROW_N / 4; i4 += THREADS_SS) {
        const float4 v = xr[i4];
        atomicAdd(&fh[(__float_as_uint(v.x) & 0x7FFFFFFFu) >> KSHIFT], 1u);
        atomicAdd(&fh[(__float_as_uint(v.y) & 0x7FFFFFFFu) >> KSHIFT], 1u);
        atomicAdd(&fh[(__float_as_uint(v.z) & 0x7FFFFFFFu) >> KSHIFT], 1u);
        atomicAdd(&fh[(__float_as_uint(v.w) & 0x7FFFFFFFu) >> KSHIFT], 1u);
    }
    __syncthreads();

    const int PER = NBUCKET / THREADS_SS;   // 8
    unsigned s = 0;
#pragma unroll
    for (int i = 0; i < PER; ++i) s += fh[NBUCKET - 1 - (t * PER + i)];
    unsigned incl = s;
#pragma unroll
    for (int d = 1; d < 64; d <<= 1) {
        const unsigned nv = __shfl_up(incl, d);
        if (lane >= d) incl += nv;
    }
    if (lane == 63) wsum[w] = incl;
    __syncthreads();
    if (t < 8) {
        const unsigned v0 = wsum[t];
        unsigned inc2 = v0;
#pragma unroll
        for (int d = 1; d < 8; d <<= 1) {
            const unsigned nv = __shfl_up(inc2, d);
            if (t >= d) inc2 += nv;
        }
        wbase_s[t] = inc2 - v0;
    }
    __syncthreads();
    unsigned cum = wbase_s[w] + incl - s;
#pragma unroll
    for (int i = 0; i < PER; ++i) {
        const int bucket = NBUCKET - 1 - (t * PER + i);
        const unsigned c = fh[bucket];
        if (cum < K && cum + c >= K) { sb = bucket; sneed = (int)(K - cum); }
        cum += c;
    }
    __syncthreads();
    const int b = sb;
    const int need = sneed;

    for (int i4 = t; i4 < ROW_N / 4; i4 += THREADS_SS) {
        const float4 v = xr[i4];
        const unsigned bits4[4] = {__float_as_uint(v.x), __float_as_uint(v.y),
                                   __float_as_uint(v.z), __float_as_uint(v.w)};
#pragma unroll
        for (int c = 0; c < 4; ++c) {
            const int key = (int)((bits4[c] & 0x7FFFFFFFu) >> KSHIFT);
            if (key > b) {
                rout[i4 * 4 + c] = __uint_as_float(bits4[c]);
            } else if (key == b) {
                const unsigned p = atomicAdd(&tcnt, 1u);
                if (p < FB_TIE_CAP) { ftidx[p] = (unsigned)(i4 * 4 + c); ftbits[p] = bits4[c]; }
            }
        }
    }
    __syncthreads();
    const int c = (int)(tcnt < (unsigned)FB_TIE_CAP ? tcnt : (unsigned)FB_TIE_CAP);
    for (int i = t; i < c; i += THREADS_SS) {
        const unsigned bits = ftbits[i], idx = ftidx[i];
        const uint64_t key = ((uint64_t)(bits & 0x7FFFFFFFu) << 32) | (uint64_t)(~idx);
        int rank = 0;
        for (int j = 0; j < c; ++j) {
            const uint64_t kj = ((uint64_t)(ftbits[j] & 0x7FFFFFFFu) << 32) | (uint64_t)(~ftidx[j]);
            rank += (kj > key) ? 1 : 0;
        }
        if (rank < need) rout[idx] = __uint_as_float(bits);
    }
}

extern "C" void kernel_launch(void* const* d_in, const int* in_sizes, int n_in,
                              void* d_out, int out_size, void* d_ws, size_t ws_size,
                              hipStream_t stream) {
    const float* x = (const float*)d_in[0];
    const int* topk = (const int*)d_in[1];
    float* out = (float*)d_out;
    char* ws = (char*)d_ws;

    unsigned* wave_cnt = (unsigned*)(ws + OFF_WCNT);
    uint2* cand        = (uint2*)(ws + OFF_CAND);

    // no memset: every workspace slot we read is unconditionally written

    dim3 gridA(BLOCKS_PER_ROW, B);  // 16 x 128 = 2048 blocks
    scan_zero_kernel<<<gridA, THREADS, 0, stream>>>(x, out, wave_cnt, cand);
    select_scatter_kernel<<<B, THREADS_SS, 0, stream>>>(x, cand, wave_cnt, topk, out);
}